// Round 2
// baseline (449.606 us; speedup 1.0000x reference)
//
#include <hip/hip_runtime.h>

#define NN 1024
#define DD 40
#define GG 32
#define SS 32
#define MAXIT 8

// ---- workspace layout (float offsets) ----
#define OFF_Y    0
#define OFF_X    (OFF_Y + GG*NN)
#define OFF_R    (OFF_X + GG*NN)
#define OFF_P    (OFF_R + GG*NN)
#define OFF_AP   (OFF_P + GG*NN)            /* [2][G][N] */
#define OFF_W    (OFF_AP + 2*GG*NN)
#define OFF_Q    (OFF_W + GG*NN)
#define OFF_MINV (OFF_Q + GG*NN)            /* [G][D][D] */
#define OFF_HSC  (OFF_MINV + GG*DD*DD)      /* [G][D] */
#define OFF_DET  (OFF_HSC + GG*DD)
#define OFF_RS   (OFF_DET + GG)
#define OFF_RS0  (OFF_RS + GG)
#define OFF_FLAG (OFF_RS0 + GG)             /* int[G] */

__device__ __forceinline__ float block_reduce_sum(float v, float* red) {
  // wave-64 butterfly
  for (int off = 32; off > 0; off >>= 1) v += __shfl_down(v, off);
  __syncthreads();
  int lane = threadIdx.x & 63, wid = threadIdx.x >> 6;
  if (lane == 0) red[wid] = v;
  __syncthreads();
  float s = 0.f;
  if (threadIdx.x == 0) {
    int nw = (blockDim.x + 63) >> 6;
    for (int k = 0; k < nw; ++k) s += red[k];
  }
  return s; // valid on thread 0 only
}

// ---- per-g small solves: det(cov_su*diag(1/sc)+I), inv(cov_su+diag(sc)), hsc ----
__global__ __launch_bounds__(64)
void k_small(const float* __restrict__ cov_su, const float* __restrict__ eq_scales,
             float* __restrict__ Minv, float* __restrict__ det,
             float* __restrict__ hsc, float* __restrict__ rs, int* __restrict__ flag) {
  int g = blockIdx.x, t = threadIdx.x;
  __shared__ float A[DD][DD + 1];
  __shared__ float Aug[DD][2 * DD + 1];
  __shared__ int pr_s;
  __shared__ float detv_s;

  // ---- determinant of B = cov_su * diag(1/scales_g) + I ----
  for (int idx = t; idx < DD * DD; idx += 64) {
    int k = idx / DD, m = idx % DD;
    float v = cov_su[k * DD + m] / eq_scales[g * DD + m];
    if (k == m) v += 1.f;
    A[k][m] = v;
  }
  if (t == 0) detv_s = 1.f;
  __syncthreads();
  for (int c = 0; c < DD; ++c) {
    if (t == 0) {
      int pr = c; float best = fabsf(A[c][c]);
      for (int r2 = c + 1; r2 < DD; ++r2) {
        float a = fabsf(A[r2][c]);
        if (a > best) { best = a; pr = r2; }
      }
      pr_s = pr;
      if (pr != c) detv_s = -detv_s;
    }
    __syncthreads();
    int pr = pr_s;
    if (pr != c) for (int m = t; m < DD; m += 64) {
      float tmp = A[c][m]; A[c][m] = A[pr][m]; A[pr][m] = tmp;
    }
    __syncthreads();
    float piv = A[c][c];
    if (t == 0) detv_s *= piv;
    for (int r2 = c + 1 + t; r2 < DD; r2 += 64) {
      float f = A[r2][c] / piv;
      for (int m = c; m < DD; ++m) A[r2][m] -= f * A[c][m];
    }
    __syncthreads();
  }
  if (t == 0) det[g] = detv_s;

  // ---- inverse of M = cov_su + diag(scales_g) via Gauss-Jordan ----
  for (int idx = t; idx < DD * 2 * DD; idx += 64) {
    int k = idx / (2 * DD), m = idx % (2 * DD);
    float v;
    if (m < DD) { v = cov_su[k * DD + m]; if (m == k) v += eq_scales[g * DD + k]; }
    else v = (m - DD == k) ? 1.f : 0.f;
    Aug[k][m] = v;
  }
  __syncthreads();
  for (int c = 0; c < DD; ++c) {
    if (t == 0) {
      int pr = c; float best = fabsf(Aug[c][c]);
      for (int r2 = c + 1; r2 < DD; ++r2) {
        float a = fabsf(Aug[r2][c]);
        if (a > best) { best = a; pr = r2; }
      }
      pr_s = pr;
    }
    __syncthreads();
    int pr = pr_s;
    if (pr != c) for (int m = t; m < 2 * DD; m += 64) {
      float tmp = Aug[c][m]; Aug[c][m] = Aug[pr][m]; Aug[pr][m] = tmp;
    }
    __syncthreads();
    float piv = Aug[c][c];
    __syncthreads();
    for (int m = t; m < 2 * DD; m += 64) Aug[c][m] /= piv;
    __syncthreads();
    for (int r2 = t; r2 < DD; r2 += 64) {
      if (r2 == c) continue;
      float f = Aug[r2][c];
      for (int m = 0; m < 2 * DD; ++m) Aug[r2][m] -= f * Aug[c][m];
    }
    __syncthreads();
  }
  for (int idx = t; idx < DD * DD; idx += 64) {
    int k = idx / DD, m = idx % DD;
    Minv[(g * DD + k) * DD + m] = Aug[k][DD + m];
  }
  for (int d0 = t; d0 < DD; d0 += 64) hsc[g * DD + d0] = 0.5f / eq_scales[g * DD + d0];
  if (t == 0) { rs[g] = 0.f; flag[g] = 0; }
}

// ---- init: y copy, CG init (x=0, r=p=y, rs0=y'y), w[g,i], Q[g,i] ----
__global__ __launch_bounds__(1024)
void k_init(const float* __restrict__ inputs, const float* __restrict__ outputs,
            const float* __restrict__ mu, const float* __restrict__ Minv,
            const float* __restrict__ det, const float* __restrict__ hsc,
            float* __restrict__ Y, float* __restrict__ Xv, float* __restrict__ Rv,
            float* __restrict__ Pv, float* __restrict__ Wv, float* __restrict__ Qv,
            float* __restrict__ rs, float* __restrict__ rs0) {
  int g = blockIdx.x, i = threadIdx.x;
  __shared__ float Ml[DD * DD];
  __shared__ float hl[DD];
  __shared__ float red[16];
  for (int idx = i; idx < DD * DD; idx += 1024) Ml[idx] = Minv[g * DD * DD + idx];
  if (i < DD) hl[i] = hsc[g * DD + i];
  __syncthreads();

  float y = outputs[i * SS + g];
  float nu[DD];
  float q = 0.f;
  for (int d0 = 0; d0 < DD; ++d0) {
    float xv = inputs[i * DD + d0];
    nu[d0] = xv - mu[d0];
    q = fmaf(hl[d0] * xv, xv, q);
  }
  float quad = 0.f;
  for (int k = 0; k < DD; ++k) {
    float s = 0.f;
    for (int m = 0; m < DD; ++m) s = fmaf(Ml[k * DD + m], nu[m], s);
    quad = fmaf(nu[k], s, quad);
  }
  float w = det[g] * __expf(-0.5f * quad);

  int gi = g * NN + i;
  Y[gi] = y; Xv[gi] = 0.f; Rv[gi] = y; Pv[gi] = y; Wv[gi] = w; Qv[gi] = q;

  float t2 = block_reduce_sum(y * y, red);
  if (i == 0) { rs[g] = t2; rs0[g] = t2; }
}

// ---- matvec: AP[half][g][i] = coeff_g * sum_{j in half} exp(2*dot - qi - qj) * p_j ----
__global__ __launch_bounds__(64)
void k_mv(const float* __restrict__ inputs, const float* __restrict__ eq_coeff,
          const float* __restrict__ Pv, const float* __restrict__ Qv,
          const float* __restrict__ hsc, float* __restrict__ AP,
          const int* __restrict__ flag) {
  int g = blockIdx.z;
  if (flag[g]) return;
  int t = threadIdx.x;
  int i = blockIdx.x * 64 + t;
  int jbase0 = blockIdx.y * 512;

  __shared__ float xis[64][DD];
  __shared__ float xjs[64][DD];
  __shared__ float pj[64], qj[64];
  __shared__ float hl[DD];

  if (t < DD) hl[t] = hsc[g * DD + t];
  for (int idx = t; idx < 64 * DD; idx += 64)
    xis[idx / DD][idx % DD] = inputs[blockIdx.x * 64 * DD + idx];
  __syncthreads();

  float ai[DD];
  #pragma unroll
  for (int d0 = 0; d0 < DD; ++d0) ai[d0] = hl[d0] * xis[t][d0];
  float qi = Qv[g * NN + i];
  float acc = 0.f;

  for (int c0 = 0; c0 < 512; c0 += 64) {
    __syncthreads();
    int jb = jbase0 + c0;
    for (int idx = t; idx < 64 * DD; idx += 64)
      xjs[idx / DD][idx % DD] = inputs[jb * DD + idx];
    pj[t] = Pv[g * NN + jb + t];
    qj[t] = Qv[g * NN + jb + t];
    __syncthreads();
    for (int j = 0; j < 64; ++j) {
      float dot = 0.f;
      #pragma unroll
      for (int d0 = 0; d0 < DD; ++d0) dot = fmaf(ai[d0], xjs[j][d0], dot);
      float e = __expf(2.f * dot - qi - qj[j]);
      acc = fmaf(e, pj[j], acc);
    }
  }
  AP[(blockIdx.y * GG + g) * NN + i] = eq_coeff[g] * acc;
}

// ---- CG update (one block per g) ----
__global__ __launch_bounds__(1024)
void k_cg_update(const float* __restrict__ eq_noise, float* __restrict__ Xv,
                 float* __restrict__ Rv, float* __restrict__ Pv,
                 const float* __restrict__ AP, float* __restrict__ rs,
                 const float* __restrict__ rs0, int* __restrict__ flag) {
  int g = blockIdx.x;
  if (flag[g]) return;
  int i = threadIdx.x;
  int gi = g * NN + i;
  __shared__ float red[16];
  __shared__ float sc0, sc1;

  float p = Pv[gi];
  float ap = AP[g * NN + i] + AP[(GG + g) * NN + i] + eq_noise[g] * p;
  float pap = block_reduce_sum(p * ap, red);
  if (i == 0) sc0 = pap;
  __syncthreads();
  float pAp = sc0;
  float rsold = rs[g];
  if (!(pAp > 0.f) || !(rsold > 0.f)) { if (i == 0) flag[g] = 1; return; }

  float alpha = rsold / pAp;
  float x = Xv[gi] + alpha * p;
  float r = Rv[gi] - alpha * ap;
  float rsn = block_reduce_sum(r * r, red);
  if (i == 0) sc1 = rsn;
  __syncthreads();
  rsn = sc1;
  float beta = rsn / rsold;
  Xv[gi] = x; Rv[gi] = r; Pv[gi] = r + beta * p;
  if (i == 0) {
    rs[g] = rsn;
    if (!(rsn > rs0[g] * 1e-24f)) flag[g] = 1;
  }
}

// ---- final: out[g] = sum_i x[g,i] * w[g,i] ----
__global__ __launch_bounds__(1024)
void k_final(const float* __restrict__ Xv, const float* __restrict__ Wv,
             float* __restrict__ out) {
  int g = blockIdx.x, i = threadIdx.x;
  __shared__ float red[16];
  float s = block_reduce_sum(Xv[g * NN + i] * Wv[g * NN + i], red);
  if (i == 0) out[g] = s;
}

extern "C" void kernel_launch(void* const* d_in, const int* in_sizes, int n_in,
                              void* d_out, int out_size, void* d_ws, size_t ws_size,
                              hipStream_t stream) {
  const float* inputs   = (const float*)d_in[0];
  const float* outputs  = (const float*)d_in[1];
  const float* eq_coeff = (const float*)d_in[2];
  const float* eq_scales= (const float*)d_in[3];
  const float* eq_noise = (const float*)d_in[4];
  const float* mu       = (const float*)d_in[5];
  const float* cov_su   = (const float*)d_in[6];

  float* W = (float*)d_ws;
  float* Y    = W + OFF_Y;
  float* Xv   = W + OFF_X;
  float* Rv   = W + OFF_R;
  float* Pv   = W + OFF_P;
  float* AP   = W + OFF_AP;
  float* Wv   = W + OFF_W;
  float* Qv   = W + OFF_Q;
  float* Minv = W + OFF_MINV;
  float* hsc  = W + OFF_HSC;
  float* det  = W + OFF_DET;
  float* rs   = W + OFF_RS;
  float* rs0  = W + OFF_RS0;
  int*   flag = (int*)(W + OFF_FLAG);

  k_small<<<GG, 64, 0, stream>>>(cov_su, eq_scales, Minv, det, hsc, rs, flag);
  k_init<<<GG, 1024, 0, stream>>>(inputs, outputs, mu, Minv, det, hsc,
                                  Y, Xv, Rv, Pv, Wv, Qv, rs, rs0);
  for (int it = 0; it < MAXIT; ++it) {
    k_mv<<<dim3(NN / 64, 2, GG), 64, 0, stream>>>(inputs, eq_coeff, Pv, Qv, hsc, AP, flag);
    k_cg_update<<<GG, 1024, 0, stream>>>(eq_noise, Xv, Rv, Pv, AP, rs, rs0, flag);
  }
  k_final<<<GG, 1024, 0, stream>>>(Xv, Wv, (float*)d_out);
}

// Round 3
// 185.282 us; speedup vs baseline: 2.4266x; 2.4266x over previous
//
#include <hip/hip_runtime.h>

#define NN 1024
#define DD 40
#define GG 32
#define SS 32
#define MAXIT 4

// ---- workspace layout (float offsets) ----
#define OFF_X    0
#define OFF_R    (OFF_X + GG*NN)
#define OFF_P    (OFF_R + GG*NN)
#define OFF_AP   (OFF_P + GG*NN)            /* [2][G][N] */
#define OFF_W    (OFF_AP + 2*GG*NN)
#define OFF_Q    (OFF_W + GG*NN)
#define OFF_MINV (OFF_Q + GG*NN)            /* [G][D][D] */
#define OFF_HSC  (OFF_MINV + GG*DD*DD)      /* [G][D] */
#define OFF_DET  (OFF_HSC + GG*DD)
#define OFF_RS   (OFF_DET + GG)
#define OFF_RS0  (OFF_RS + GG)
#define OFF_FLAG (OFF_RS0 + GG)             /* int[G] */

__device__ __forceinline__ float block_reduce_sum(float v, float* red) {
  for (int off = 32; off > 0; off >>= 1) v += __shfl_down(v, off);
  __syncthreads();
  int lane = threadIdx.x & 63, wid = threadIdx.x >> 6;
  if (lane == 0) red[wid] = v;
  __syncthreads();
  float s = 0.f;
  if (threadIdx.x == 0) {
    int nw = (blockDim.x + 63) >> 6;
    for (int k = 0; k < nw; ++k) s += red[k];
  }
  return s; // valid on thread 0 only
}

// ---- per-g small solve, element-parallel Gauss-Jordan, no pivoting (M is SPD).
// M = cov_su + diag(scales_g). det(cov_su*diag(1/s)+I) = det(M)/prod(s).
__global__ __launch_bounds__(256)
void k_small(const float* __restrict__ cov_su, const float* __restrict__ eq_scales,
             float* __restrict__ Minv, float* __restrict__ det,
             float* __restrict__ hsc, float* __restrict__ rs, int* __restrict__ flag) {
  int g = blockIdx.x, t = threadIdx.x;
  __shared__ float Aug[DD][2 * DD + 1];
  __shared__ float colv[DD];
  __shared__ float pivs[DD];

  for (int idx = t; idx < DD * 2 * DD; idx += 256) {
    int r = idx / (2 * DD), m = idx % (2 * DD);
    float v;
    if (m < DD) { v = cov_su[r * DD + m]; if (m == r) v += eq_scales[g * DD + r]; }
    else v = (m - DD == r) ? 1.f : 0.f;
    Aug[r][m] = v;
  }
  __syncthreads();

  for (int c = 0; c < DD; ++c) {
    float piv = Aug[c][c];          // broadcast read, all threads
    float rp = 1.f / piv;
    if (t == 0) pivs[c] = piv;
    __syncthreads();                // everyone has piv before row c is scaled
    if (t < 2 * DD) Aug[c][t] *= rp;
    if (t >= 128 && t < 128 + DD) { // capture column c (rows != c untouched above)
      int r = t - 128;
      if (r != c) colv[r] = Aug[r][c];
    }
    __syncthreads();
    for (int idx = t; idx < DD * 2 * DD; idx += 256) {
      int r = idx / (2 * DD), m = idx % (2 * DD);
      if (r != c) Aug[r][m] = fmaf(-colv[r], Aug[c][m], Aug[r][m]);
    }
    __syncthreads();
  }

  for (int idx = t; idx < DD * DD; idx += 256) {
    int r = idx / DD, m = idx % DD;
    Minv[(g * DD + r) * DD + m] = Aug[r][DD + m];
  }
  for (int d0 = t; d0 < DD; d0 += 256) hsc[g * DD + d0] = 0.5f / eq_scales[g * DD + d0];
  if (t == 0) {
    float dv = 1.f;
    for (int c = 0; c < DD; ++c) dv *= pivs[c];
    for (int m = 0; m < DD; ++m) dv /= eq_scales[g * DD + m];
    det[g] = dv;
    rs[g] = 0.f;
    flag[g] = 0;
  }
}

// ---- init: CG init (x=0, r=p=y, rs0=y'y), w[g,i], Q[g,i] ----
__global__ __launch_bounds__(1024)
void k_init(const float* __restrict__ inputs, const float* __restrict__ outputs,
            const float* __restrict__ mu, const float* __restrict__ Minv,
            const float* __restrict__ det, const float* __restrict__ hsc,
            float* __restrict__ Xv, float* __restrict__ Rv,
            float* __restrict__ Pv, float* __restrict__ Wv, float* __restrict__ Qv,
            float* __restrict__ rs, float* __restrict__ rs0) {
  int g = blockIdx.x, i = threadIdx.x;
  __shared__ float Ml[DD * DD];
  __shared__ float hl[DD];
  __shared__ float red[16];
  for (int idx = i; idx < DD * DD; idx += 1024) Ml[idx] = Minv[g * DD * DD + idx];
  if (i < DD) hl[i] = hsc[g * DD + i];
  __syncthreads();

  float y = outputs[i * SS + g];
  float nu[DD];
  float q = 0.f;
  #pragma unroll
  for (int d0 = 0; d0 < DD; ++d0) {
    float xv = inputs[i * DD + d0];
    nu[d0] = xv - mu[d0];
    q = fmaf(hl[d0] * xv, xv, q);
  }
  float quad = 0.f;
  #pragma unroll
  for (int k = 0; k < DD; ++k) {
    float s = 0.f;
    #pragma unroll
    for (int m = 0; m < DD; ++m) s = fmaf(Ml[k * DD + m], nu[m], s);
    quad = fmaf(nu[k], s, quad);
  }
  float w = det[g] * __expf(-0.5f * quad);

  int gi = g * NN + i;
  Xv[gi] = 0.f; Rv[gi] = y; Pv[gi] = y; Wv[gi] = w; Qv[gi] = q;

  float t2 = block_reduce_sum(y * y, red);
  if (i == 0) { rs[g] = t2; rs0[g] = t2; }
}

// ---- matvec: AP[half][g][i] = coeff_g * sum_{j in half} exp(2*dot - qi - qj) * p_j ----
__global__ __launch_bounds__(64)
void k_mv(const float* __restrict__ inputs, const float* __restrict__ eq_coeff,
          const float* __restrict__ Pv, const float* __restrict__ Qv,
          const float* __restrict__ hsc, float* __restrict__ AP,
          const int* __restrict__ flag) {
  int g = blockIdx.z;
  if (flag[g]) return;
  int t = threadIdx.x;
  int i = blockIdx.x * 64 + t;
  int jbase0 = blockIdx.y * 512;

  __shared__ float xis[64][DD];
  __shared__ float xjs[64][DD];
  __shared__ float pj[64], qj[64];
  __shared__ float hl[DD];

  if (t < DD) hl[t] = hsc[g * DD + t];
  for (int idx = t; idx < 64 * DD; idx += 64)
    xis[idx / DD][idx % DD] = inputs[blockIdx.x * 64 * DD + idx];
  __syncthreads();

  float ai[DD];
  #pragma unroll
  for (int d0 = 0; d0 < DD; ++d0) ai[d0] = hl[d0] * xis[t][d0];
  float qi = Qv[g * NN + i];
  float acc = 0.f;

  for (int c0 = 0; c0 < 512; c0 += 64) {
    __syncthreads();
    int jb = jbase0 + c0;
    for (int idx = t; idx < 64 * DD; idx += 64)
      xjs[idx / DD][idx % DD] = inputs[jb * DD + idx];
    pj[t] = Pv[g * NN + jb + t];
    qj[t] = Qv[g * NN + jb + t];
    __syncthreads();
    #pragma unroll 4
    for (int j = 0; j < 64; ++j) {
      float dot = 0.f;
      #pragma unroll
      for (int d0 = 0; d0 < DD; ++d0) dot = fmaf(ai[d0], xjs[j][d0], dot);
      float e = __expf(2.f * dot - qi - qj[j]);
      acc = fmaf(e, pj[j], acc);
    }
  }
  AP[(blockIdx.y * GG + g) * NN + i] = eq_coeff[g] * acc;
}

// ---- CG update (one block per g) ----
__global__ __launch_bounds__(1024)
void k_cg_update(const float* __restrict__ eq_noise, float* __restrict__ Xv,
                 float* __restrict__ Rv, float* __restrict__ Pv,
                 const float* __restrict__ AP, float* __restrict__ rs,
                 const float* __restrict__ rs0, int* __restrict__ flag) {
  int g = blockIdx.x;
  if (flag[g]) return;
  int i = threadIdx.x;
  int gi = g * NN + i;
  __shared__ float red[16];
  __shared__ float sc0, sc1;

  float p = Pv[gi];
  float ap = AP[g * NN + i] + AP[(GG + g) * NN + i] + eq_noise[g] * p;
  float pap = block_reduce_sum(p * ap, red);
  if (i == 0) sc0 = pap;
  __syncthreads();
  float pAp = sc0;
  float rsold = rs[g];
  if (!(pAp > 0.f) || !(rsold > 0.f)) { if (i == 0) flag[g] = 1; return; }

  float alpha = rsold / pAp;
  float x = Xv[gi] + alpha * p;
  float r = Rv[gi] - alpha * ap;
  float rsn = block_reduce_sum(r * r, red);
  if (i == 0) sc1 = rsn;
  __syncthreads();
  rsn = sc1;
  float beta = rsn / rsold;
  Xv[gi] = x; Rv[gi] = r; Pv[gi] = r + beta * p;
  if (i == 0) {
    rs[g] = rsn;
    if (!(rsn > rs0[g] * 1e-12f)) flag[g] = 1;   // f32 CG stagnates ~1e-14; triggers after it converges
  }
}

// ---- final: out[g] = sum_i x[g,i] * w[g,i] ----
__global__ __launch_bounds__(1024)
void k_final(const float* __restrict__ Xv, const float* __restrict__ Wv,
             float* __restrict__ out) {
  int g = blockIdx.x, i = threadIdx.x;
  __shared__ float red[16];
  float s = block_reduce_sum(Xv[g * NN + i] * Wv[g * NN + i], red);
  if (i == 0) out[g] = s;
}

extern "C" void kernel_launch(void* const* d_in, const int* in_sizes, int n_in,
                              void* d_out, int out_size, void* d_ws, size_t ws_size,
                              hipStream_t stream) {
  const float* inputs   = (const float*)d_in[0];
  const float* outputs  = (const float*)d_in[1];
  const float* eq_coeff = (const float*)d_in[2];
  const float* eq_scales= (const float*)d_in[3];
  const float* eq_noise = (const float*)d_in[4];
  const float* mu       = (const float*)d_in[5];
  const float* cov_su   = (const float*)d_in[6];

  float* W = (float*)d_ws;
  float* Xv   = W + OFF_X;
  float* Rv   = W + OFF_R;
  float* Pv   = W + OFF_P;
  float* AP   = W + OFF_AP;
  float* Wv   = W + OFF_W;
  float* Qv   = W + OFF_Q;
  float* Minv = W + OFF_MINV;
  float* hsc  = W + OFF_HSC;
  float* det  = W + OFF_DET;
  float* rs   = W + OFF_RS;
  float* rs0  = W + OFF_RS0;
  int*   flag = (int*)(W + OFF_FLAG);

  k_small<<<GG, 256, 0, stream>>>(cov_su, eq_scales, Minv, det, hsc, rs, flag);
  k_init<<<GG, 1024, 0, stream>>>(inputs, outputs, mu, Minv, det, hsc,
                                  Xv, Rv, Pv, Wv, Qv, rs, rs0);
  for (int it = 0; it < MAXIT; ++it) {
    k_mv<<<dim3(NN / 64, 2, GG), 64, 0, stream>>>(inputs, eq_coeff, Pv, Qv, hsc, AP, flag);
    k_cg_update<<<GG, 1024, 0, stream>>>(eq_noise, Xv, Rv, Pv, AP, rs, rs0, flag);
  }
  k_final<<<GG, 1024, 0, stream>>>(Xv, Wv, (float*)d_out);
}

// Round 4
// 138.782 us; speedup vs baseline: 3.2397x; 1.3351x over previous
//
#include <hip/hip_runtime.h>

#define NN 1024
#define DD 40
#define NQ 10            /* DD/4 */
#define GG 32
#define SS 32
#define MAXIT 2
#define IB 128           /* i-rows per k_mv block */
#define JCHUNK 128

// ---- workspace layout (float offsets) — identical footprint to round 2 ----
#define OFF_X    0
#define OFF_R    (OFF_X + GG*NN)
#define OFF_P    (OFF_R + GG*NN)
#define OFF_AP   (OFF_P + GG*NN)            /* [2][G][N] */
#define OFF_W    (OFF_AP + 2*GG*NN)
#define OFF_Q    (OFF_W + GG*NN)
#define OFF_MINV (OFF_Q + GG*NN)            /* [G][D][D] */
#define OFF_HSC  (OFF_MINV + GG*DD*DD)      /* [G][D] */
#define OFF_DET  (OFF_HSC + GG*DD)
#define OFF_RS   (OFF_DET + GG)
#define OFF_RS0  (OFF_RS + GG)
#define OFF_FLAG (OFF_RS0 + GG)             /* int[G] */

__device__ __forceinline__ float block_reduce_sum(float v, float* red) {
  for (int off = 32; off > 0; off >>= 1) v += __shfl_down(v, off);
  __syncthreads();
  int lane = threadIdx.x & 63, wid = threadIdx.x >> 6;
  if (lane == 0) red[wid] = v;
  __syncthreads();
  float s = 0.f;
  if (threadIdx.x == 0) {
    int nw = (blockDim.x + 63) >> 6;
    for (int k = 0; k < nw; ++k) s += red[k];
  }
  return s; // valid on thread 0 only
}

// ---- per-g small solve, element-parallel Gauss-Jordan, no pivoting (M is SPD).
// M = cov_su + diag(scales_g). det(cov_su*diag(1/s)+I) = det(M)/prod(s).
__global__ __launch_bounds__(256)
void k_small(const float* __restrict__ cov_su, const float* __restrict__ eq_scales,
             float* __restrict__ Minv, float* __restrict__ det,
             float* __restrict__ hsc, float* __restrict__ rs,
             float* __restrict__ rs0, int* __restrict__ flag) {
  int g = blockIdx.x, t = threadIdx.x;
  __shared__ float Aug[DD][2 * DD + 1];
  __shared__ float colv[DD];
  __shared__ float pivs[DD];

  for (int idx = t; idx < DD * 2 * DD; idx += 256) {
    int r = idx / (2 * DD), m = idx % (2 * DD);
    float v;
    if (m < DD) { v = cov_su[r * DD + m]; if (m == r) v += eq_scales[g * DD + r]; }
    else v = (m - DD == r) ? 1.f : 0.f;
    Aug[r][m] = v;
  }
  __syncthreads();

  for (int c = 0; c < DD; ++c) {
    float piv = Aug[c][c];
    float rp = 1.f / piv;
    if (t == 0) pivs[c] = piv;
    __syncthreads();
    if (t < 2 * DD) Aug[c][t] *= rp;
    if (t >= 128 && t < 128 + DD) {
      int r = t - 128;
      if (r != c) colv[r] = Aug[r][c];
    }
    __syncthreads();
    for (int idx = t; idx < DD * 2 * DD; idx += 256) {
      int r = idx / (2 * DD), m = idx % (2 * DD);
      if (r != c) Aug[r][m] = fmaf(-colv[r], Aug[c][m], Aug[r][m]);
    }
    __syncthreads();
  }

  for (int idx = t; idx < DD * DD; idx += 256) {
    int r = idx / DD, m = idx % DD;
    Minv[(g * DD + r) * DD + m] = Aug[r][DD + m];
  }
  for (int d0 = t; d0 < DD; d0 += 256) hsc[g * DD + d0] = 0.5f / eq_scales[g * DD + d0];
  if (t == 0) {
    float dv = 1.f;
    for (int c = 0; c < DD; ++c) dv *= pivs[c];
    for (int m = 0; m < DD; ++m) dv /= eq_scales[g * DD + m];
    det[g] = dv;
    rs[g] = 0.f;
    rs0[g] = 0.f;
    flag[g] = 0;
  }
}

// ---- init: CG init (x=0, r=p=y, rs0 += y'y), w[g,i], Q[g,i]; grid (8 ichunks, 32 g) ----
__global__ __launch_bounds__(128)
void k_init(const float* __restrict__ inputs, const float* __restrict__ outputs,
            const float* __restrict__ mu, const float* __restrict__ Minv,
            const float* __restrict__ det, const float* __restrict__ hsc,
            float* __restrict__ Xv, float* __restrict__ Rv,
            float* __restrict__ Pv, float* __restrict__ Wv, float* __restrict__ Qv,
            float* __restrict__ rs, float* __restrict__ rs0) {
  const int g = blockIdx.y;
  const int i = blockIdx.x * 128 + threadIdx.x;
  const int t = threadIdx.x;
  __shared__ float4 Ml4[DD * NQ];
  __shared__ float4 hl4[NQ];
  __shared__ float red[16];

  for (int idx = t; idx < DD * NQ; idx += 128)
    Ml4[idx] = *(const float4*)&Minv[g * DD * DD + idx * 4];
  if (t < NQ) hl4[t] = *(const float4*)&hsc[g * DD + t * 4];
  __syncthreads();

  float4 nu4[NQ];
  float q = 0.f;
  #pragma unroll
  for (int mq = 0; mq < NQ; ++mq) {
    float4 x = *(const float4*)&inputs[i * DD + mq * 4];
    float4 m = *(const float4*)&mu[mq * 4];
    float4 h = hl4[mq];
    nu4[mq].x = x.x - m.x; nu4[mq].y = x.y - m.y;
    nu4[mq].z = x.z - m.z; nu4[mq].w = x.w - m.w;
    q = fmaf(h.x * x.x, x.x, q);
    q = fmaf(h.y * x.y, x.y, q);
    q = fmaf(h.z * x.z, x.z, q);
    q = fmaf(h.w * x.w, x.w, q);
  }

  float quad = 0.f;
  #pragma unroll
  for (int k = 0; k < DD; ++k) {
    float s = 0.f;
    #pragma unroll
    for (int mq = 0; mq < NQ; ++mq) {
      float4 mm = Ml4[k * NQ + mq];
      float4 nn = nu4[mq];
      s = fmaf(mm.x, nn.x, s);
      s = fmaf(mm.y, nn.y, s);
      s = fmaf(mm.z, nn.z, s);
      s = fmaf(mm.w, nn.w, s);
    }
    // static component select (k is a compile-time constant in the unrolled loop)
    float4 nk4 = nu4[k >> 2];
    float nk = ((k & 3) == 0) ? nk4.x : ((k & 3) == 1) ? nk4.y : ((k & 3) == 2) ? nk4.z : nk4.w;
    quad = fmaf(nk, s, quad);
  }
  float w = det[g] * __expf(-0.5f * quad);

  float y = outputs[i * SS + g];
  int gi = g * NN + i;
  Xv[gi] = 0.f; Rv[gi] = y; Pv[gi] = y; Wv[gi] = w; Qv[gi] = q;

  float t2 = block_reduce_sum(y * y, red);
  if (t == 0) { atomicAdd(&rs[g], t2); atomicAdd(&rs0[g], t2); }
}

// ---- matvec: register-tiled 8i x 8j, SoA-skewed LDS, ds_read_b128 ----
// AP[slice][g][i] = coeff_g * sum_{j in slice} exp(2*dot - qi - qj) * p_j
__global__ __launch_bounds__(256)
void k_mv(const float* __restrict__ inputs, const float* __restrict__ eq_coeff,
          const float* __restrict__ Pv, const float* __restrict__ Qv,
          const float* __restrict__ hsc, float* __restrict__ AP,
          const int* __restrict__ flag) {
  const int g = blockIdx.z;
  if (flag[g]) return;
  const int t = threadIdx.x;
  const int ti = t & 15;           // i-group (16 x 8 rows = 128 i)
  const int tj = t >> 4;           // j-group (16 x 8 cols = 128 j per chunk)
  const int ib = blockIdx.x * IB;
  const int js = blockIdx.y;       // j-slice (0..1), 512 j each
  const int jbase = js * (NN / 2);

  __shared__ float4 A4[NQ * 144];  // [d4][skewed row], row' = row + (row>>3)
  __shared__ float4 B4[NQ * 144];
  __shared__ float pjs[JCHUNK];
  __shared__ float qjs[JCHUNK];

  // stage A = h .* x for rows [ib, ib+128)
  for (int idx = t; idx < IB * NQ; idx += 256) {
    int row = idx / NQ, d4 = idx % NQ;
    float4 x = *(const float4*)&inputs[(ib + row) * DD + d4 * 4];
    float4 h = *(const float4*)&hsc[g * DD + d4 * 4];
    float4 a;
    a.x = h.x * x.x; a.y = h.y * x.y; a.z = h.z * x.z; a.w = h.w * x.w;
    A4[d4 * 144 + row + (row >> 3)] = a;
  }
  float qi[8];
  #pragma unroll
  for (int r = 0; r < 8; ++r) qi[r] = Qv[g * NN + ib + ti * 8 + r];
  float facc[8];
  #pragma unroll
  for (int r = 0; r < 8; ++r) facc[r] = 0.f;

  for (int ch = 0; ch < (NN / 2) / JCHUNK; ++ch) {
    const int jb = jbase + ch * JCHUNK;
    __syncthreads();   // previous chunk's readers done before overwriting B4/pjs/qjs
    for (int idx = t; idx < JCHUNK * NQ; idx += 256) {
      int row = idx / NQ, d4 = idx % NQ;
      B4[d4 * 144 + row + (row >> 3)] = *(const float4*)&inputs[(jb + row) * DD + d4 * 4];
    }
    if (t < JCHUNK) pjs[t] = Pv[g * NN + jb + t];
    else if (t < 2 * JCHUNK) qjs[t - JCHUNK] = Qv[g * NN + jb + (t - JCHUNK)];
    __syncthreads();

    float dot[8][8];
    #pragma unroll
    for (int r = 0; r < 8; ++r)
      #pragma unroll
      for (int c = 0; c < 8; ++c) dot[r][c] = 0.f;

    #pragma unroll
    for (int d4 = 0; d4 < NQ; ++d4) {
      float4 a8[8], b8[8];
      #pragma unroll
      for (int r = 0; r < 8; ++r) a8[r] = A4[d4 * 144 + ti * 9 + r];
      #pragma unroll
      for (int c = 0; c < 8; ++c) b8[c] = B4[d4 * 144 + tj * 9 + c];
      #pragma unroll
      for (int r = 0; r < 8; ++r)
        #pragma unroll
        for (int c = 0; c < 8; ++c) {
          dot[r][c] = fmaf(a8[r].x, b8[c].x, dot[r][c]);
          dot[r][c] = fmaf(a8[r].y, b8[c].y, dot[r][c]);
          dot[r][c] = fmaf(a8[r].z, b8[c].z, dot[r][c]);
          dot[r][c] = fmaf(a8[r].w, b8[c].w, dot[r][c]);
        }
    }

    #pragma unroll
    for (int c = 0; c < 8; ++c) {
      float qjv = qjs[tj * 8 + c], pjv = pjs[tj * 8 + c];
      #pragma unroll
      for (int r = 0; r < 8; ++r) {
        float e = __expf(2.f * dot[r][c] - qi[r] - qjv);
        facc[r] = fmaf(e, pjv, facc[r]);
      }
    }
  }

  // reduce facc over the 16 tj-groups (alias red onto B4; 128*17 <= 5760 floats)
  __syncthreads();
  float* red = (float*)B4;
  #pragma unroll
  for (int r = 0; r < 8; ++r) red[(ti * 8 + r) * 17 + tj] = facc[r];
  __syncthreads();
  if (t < IB) {
    float s = 0.f;
    #pragma unroll
    for (int k = 0; k < 16; ++k) s += red[t * 17 + k];
    AP[(js * GG + g) * NN + ib + t] = eq_coeff[g] * s;
  }
}

// ---- CG update with fused final-output write ----
__global__ __launch_bounds__(1024)
void k_cg_update(const float* __restrict__ eq_noise, float* __restrict__ Xv,
                 float* __restrict__ Rv, float* __restrict__ Pv,
                 const float* __restrict__ AP, float* __restrict__ rs,
                 const float* __restrict__ rs0, int* __restrict__ flag,
                 const float* __restrict__ Wv, float* __restrict__ out, int force) {
  int g = blockIdx.x;
  if (flag[g]) return;
  int i = threadIdx.x;
  int gi = g * NN + i;
  __shared__ float red[16];
  __shared__ float sc;

  float p = Pv[gi];
  float ap = AP[gi] + AP[GG * NN + gi] + eq_noise[g] * p;
  float pap = block_reduce_sum(p * ap, red);
  if (i == 0) sc = pap;
  __syncthreads();
  float pAp = sc;
  float rsold = rs[g];

  bool dead = !(pAp > 0.f) || !(rsold > 0.f);
  float x, r;
  if (dead) { x = Xv[gi]; r = 0.f; }
  else {
    float alpha = rsold / pAp;
    x = Xv[gi] + alpha * p;
    r = Rv[gi] - alpha * ap;
  }
  float rsn = block_reduce_sum(r * r, red);
  if (i == 0) sc = rsn;
  __syncthreads();
  rsn = sc;

  bool conv = dead || !(rsn > rs0[g] * 1e-12f);
  if (!dead) {
    float beta = rsn / rsold;
    Xv[gi] = x; Rv[gi] = r; Pv[gi] = r + beta * p;
    if (i == 0) rs[g] = rsn;
  }
  if (conv || force) {
    float s = block_reduce_sum(x * Wv[gi], red);
    if (i == 0) out[g] = s;
  }
  if (i == 0 && conv) flag[g] = 1;
}

extern "C" void kernel_launch(void* const* d_in, const int* in_sizes, int n_in,
                              void* d_out, int out_size, void* d_ws, size_t ws_size,
                              hipStream_t stream) {
  const float* inputs   = (const float*)d_in[0];
  const float* outputs  = (const float*)d_in[1];
  const float* eq_coeff = (const float*)d_in[2];
  const float* eq_scales= (const float*)d_in[3];
  const float* eq_noise = (const float*)d_in[4];
  const float* mu       = (const float*)d_in[5];
  const float* cov_su   = (const float*)d_in[6];

  float* W = (float*)d_ws;
  float* Xv   = W + OFF_X;
  float* Rv   = W + OFF_R;
  float* Pv   = W + OFF_P;
  float* AP   = W + OFF_AP;
  float* Wv   = W + OFF_W;
  float* Qv   = W + OFF_Q;
  float* Minv = W + OFF_MINV;
  float* hsc  = W + OFF_HSC;
  float* det  = W + OFF_DET;
  float* rs   = W + OFF_RS;
  float* rs0  = W + OFF_RS0;
  int*   flag = (int*)(W + OFF_FLAG);

  k_small<<<GG, 256, 0, stream>>>(cov_su, eq_scales, Minv, det, hsc, rs, rs0, flag);
  k_init<<<dim3(NN / 128, GG), 128, 0, stream>>>(inputs, outputs, mu, Minv, det, hsc,
                                                 Xv, Rv, Pv, Wv, Qv, rs, rs0);
  for (int it = 0; it < MAXIT; ++it) {
    k_mv<<<dim3(NN / IB, 2, GG), 256, 0, stream>>>(inputs, eq_coeff, Pv, Qv, hsc, AP, flag);
    k_cg_update<<<GG, 1024, 0, stream>>>(eq_noise, Xv, Rv, Pv, AP, rs, rs0, flag,
                                         Wv, (float*)d_out, it == MAXIT - 1 ? 1 : 0);
  }
}